// Round 1
// 571.978 us; speedup vs baseline: 1.0022x; 1.0022x over previous
//
#include <hip/hip_runtime.h>

#define N_RAYS 262144
#define N_SAMPLES 128
#define CHUNK 8
#define TERM_EPS 1e-3f
// Early termination is data-driven: a ray's tail is dropped only once its
// measured transmittance O < TERM_EPS, so per-ray abs error <= O * max(rgb)
// < 1e-3 << 2e-2 threshold. CHUNK=8 with per-segment predicated loads:
// E[samples/ray] ~ 11.1 (P(O_8 >= 1e-3) ~ 0.38, P(O_16 >= 1e-3) ~ 2e-3),
// so expected HBM traffic ~44 MiB vs 64 MiB for CHUNK=16. Rays that never
// terminate read all 128 samples exactly.

__global__ __launch_bounds__(256) void composite_kernel(
    const float4* __restrict__ in, float* __restrict__ out) {
    const int tid  = threadIdx.x;
    const int lane = tid & 63;
    const int l8   = lane & 7;                       // lane within 8-lane segment
    const int ray  = blockIdx.x * 32 + (tid >> 3);   // 8 rays per wave, 32/block

    const float4* p = in + (size_t)ray * N_SAMPLES;
    const int leader = lane & 56;                    // segment leader lane

    // running composite map (uniform within each segment): t -> A + O*t
    float Ar = 0.f, Ag = 0.f, Ab = 0.f, O = 1.f;

    #pragma unroll 1   // keep later chunk loads behind the break / predicate
    for (int c = 0; c < N_SAMPLES / CHUNK; ++c) {
        // segment-uniform predicate: terminated rays stop fetching while the
        // wave's remaining segments finish (saves HBM bytes, not just time)
        if (O >= TERM_EPS) {
            // each 8-lane segment reads 128B contiguous from its ray
            float4 v = p[c * CHUNK + l8];
            float a  = v.x;
            float ar = a * v.y, ag = a * v.z, ab = a * v.w;
            float o  = 1.0f - a;

            // ordered affine-compose tree within the 8-lane segment:
            // after step off=k, lane i holds segment [i, i+2k)
            #pragma unroll
            for (int off = 1; off <= 4; off <<= 1) {
                float ar2 = __shfl_down(ar, off, 8);
                float ag2 = __shfl_down(ag, off, 8);
                float ab2 = __shfl_down(ab, off, 8);
                float o2  = __shfl_down(o,  off, 8);
                ar = fmaf(o, ar2, ar);
                ag = fmaf(o, ag2, ag);
                ab = fmaf(o, ab2, ab);
                o *= o2;
            }

            // broadcast the segment-composite from the leader lane
            float car = __shfl(ar, leader, 64);
            float cag = __shfl(ag, leader, 64);
            float cab = __shfl(ab, leader, 64);
            float co  = __shfl(o,  leader, 64);

            Ar = fmaf(O, car, Ar);
            Ag = fmaf(O, cag, Ag);
            Ab = fmaf(O, cab, Ab);
            O *= co;
        }

        // wave-uniform exit once all 8 rays' transmittance is negligible
        if (__ballot(O >= TERM_EPS) == 0ull) break;
    }

    // A/O are segment-uniform after the broadcasts: lanes 0..2 of each
    // segment store r,g,b in parallel (one predicated dword store each)
    if (l8 < 3) {
        float v = (l8 == 0) ? Ar : (l8 == 1) ? Ag : Ab;
        out[(size_t)ray * 3 + l8] = v;
    }
}

extern "C" void kernel_launch(void* const* d_in, const int* in_sizes, int n_in,
                              void* d_out, int out_size, void* d_ws, size_t ws_size,
                              hipStream_t stream) {
    const float4* in = (const float4*)d_in[0];
    float* out = (float*)d_out;
    composite_kernel<<<N_RAYS / 32, 256, 0, stream>>>(in, out);
}